// Round 12
// baseline (412.484 us; speedup 1.0000x reference)
//
#include <hip/hip_runtime.h>
#include <hip/hip_bf16.h>

typedef __attribute__((ext_vector_type(8))) short short8;
typedef __attribute__((ext_vector_type(4))) float floatx4;
typedef __attribute__((ext_vector_type(2))) float f32x2;
typedef unsigned short u16;
typedef unsigned int u32;

#define F_IN  256
#define F_OUT 128
#define CAP   64          // logical bucket capacity (P(deg>64) ~ 2e-18 for Poisson(16))
#define CA    24          // packed primary slots per node (csrA stride)
#define CB    40          // overflow slots per node (csrB stride), CA+CB=CAP
#define NWIN  8           // destination windows == XCD count (measured, m09)
#define PRE   24          // unconditional gather burst (>= typical wave-max degree)

__device__ __forceinline__ float bf_lo(u32 u) { return __uint_as_float(u << 16); }
__device__ __forceinline__ float bf_hi(u32 u) { return __uint_as_float(u & 0xffff0000u); }
__device__ __forceinline__ u16 f2bf(float f) {
    u32 u = __float_as_uint(f);
    u += 0x7fffu + ((u >> 16) & 1u);   // round-to-nearest-even
    return (u16)(u >> 16);
}

// ---------------- W pack + xw zero-row init + workspace zero ---------------
// gid < 32768: pack W into MFMA B-fragments.
// next 128:    zero the 8 pad rows (row N of each feature-slice) of xw.
// rest:        zero cursor+hsum+done (replaces hipMemsetAsync dispatch).
__global__ void k_pack(const float* __restrict__ W, u16* __restrict__ Wp,
                       u16* __restrict__ xw, int* __restrict__ zero0,
                       int nzero, int N) {
    int gid = blockIdx.x * 256 + threadIdx.x;
    if (gid < 32768) {
        int f = gid >> 3, j = gid & 7;
        int lane = f & 63, tt = (f >> 6) & 7, kb = f >> 9;
        int m = lane & 15, q = lane >> 4;
        Wp[(size_t)f * 8 + j] = f2bf(W[(kb * 32 + q * 8 + j) * F_OUT + tt * 16 + m]);
    } else if (gid < 32896) {
        int e = gid - 32768;
        int w = e >> 4, m = e & 15;
        xw[((size_t)w * (N + 1) + N) * 16 + m] = 0;   // bf16 zero row
    } else {
        int z = gid - 32896;
        if (z < nzero) zero0[z] = 0;
    }
}

// ---------------- FAST PATH: XCD-windowed packed-csr bucket fill -----------
// Packed csrA [N][24] (dense 96B stride) + overflow csrB [N][40] (~2% nodes).
// 2x unrolled scan, paired loads. Grid 4096 (R12: more waves in flight to
// hide L2-atomic latency; kernel is atomic-latency-bound, R0: 0.3% VALU).
__global__ void k_fillcap_xcd(const int* __restrict__ rowi, const int* __restrict__ coli,
                              int E, int npw, int N,
                              int* __restrict__ cursor,
                              int* __restrict__ csrA, int* __restrict__ csrB) {
    int grp  = blockIdx.x & (NWIN - 1);       // ~XCD id under round-robin dispatch
    int gblk = blockIdx.x >> 3;               // block index within group
    int nblk = gridDim.x >> 3;
    int lo = grp * npw;
    int hi = lo + npw; if (hi > N) hi = N;
    const int stride = nblk * blockDim.x;
    int e = gblk * blockDim.x + threadIdx.x;
    for (; e + stride < E; e += 2 * stride) {
        int d0 = coli[e],          r0 = rowi[e];
        int d1 = coli[e + stride], r1 = rowi[e + stride];
        if (d0 >= lo && d0 < hi) {
            int p = atomicAdd(&cursor[d0], 1);
            if (p < CA) csrA[d0 * CA + p] = r0;
            else if (p < CAP) csrB[d0 * CB + (p - CA)] = r0;
        }
        if (d1 >= lo && d1 < hi) {
            int p = atomicAdd(&cursor[d1], 1);
            if (p < CA) csrA[d1 * CA + p] = r1;
            else if (p < CAP) csrB[d1 * CB + (p - CA)] = r1;
        }
    }
    if (e < E) {
        int d = coli[e], r = rowi[e];
        if (d >= lo && d < hi) {
            int p = atomicAdd(&cursor[d], 1);
            if (p < CA) csrA[d * CA + p] = r;
            else if (p < CAP) csrB[d * CB + (p - CA)] = r;
        }
    }
}

// ---------------- FALLBACK PATH: exact CSR (degree + scan + fill) ----------
__global__ void k_degree(const int* __restrict__ col, int E, int* __restrict__ deg) {
    for (int e = blockIdx.x * blockDim.x + threadIdx.x; e < E; e += gridDim.x * blockDim.x)
        atomicAdd(&deg[col[e]], 1);
}

__global__ void k_blocksum(const int* __restrict__ deg, int N, int* __restrict__ bsum) {
    __shared__ int s[256];
    int base = blockIdx.x * 1024, t = threadIdx.x;
    int v = 0;
    for (int i = t; i < 1024; i += 256) { int idx = base + i; v += (idx < N) ? deg[idx] : 0; }
    s[t] = v; __syncthreads();
    for (int off = 128; off > 0; off >>= 1) {
        if (t < off) s[t] += s[t + off];
        __syncthreads();
    }
    if (t == 0) bsum[blockIdx.x] = s[0];
}

__global__ void k_rowptr(const int* __restrict__ deg, int N, const int* __restrict__ bsum,
                         int nb, int* __restrict__ rowptr) {
    __shared__ int s[256];
    __shared__ int sb[256];
    int base = blockIdx.x * 1024, t = threadIdx.x;
    sb[t] = (t < nb && t < blockIdx.x) ? bsum[t] : 0;
    __syncthreads();
    for (int off = 128; off > 0; off >>= 1) {
        if (t < off) sb[t] += sb[t + off];
        __syncthreads();
    }
    int blockbase = sb[0];
    int v[4]; int tot = 0;
#pragma unroll
    for (int j = 0; j < 4; ++j) {
        int idx = base + t * 4 + j;
        v[j] = (idx < N) ? deg[idx] : 0;
        tot += v[j];
    }
    s[t] = tot; __syncthreads();
    for (int off = 1; off < 256; off <<= 1) {
        int x = (t >= off) ? s[t - off] : 0;
        __syncthreads();
        s[t] += x;
        __syncthreads();
    }
    int prefix = blockbase + s[t] - tot;
#pragma unroll
    for (int j = 0; j < 4; ++j) {
        int idx = base + t * 4 + j;
        if (idx < N) rowptr[idx] = prefix;
        prefix += v[j];
    }
}

__global__ void k_fill(const int* __restrict__ rowi, const int* __restrict__ coli, int E,
                       const int* __restrict__ rowptr, int* __restrict__ cursor,
                       int* __restrict__ csr) {
    for (int e = blockIdx.x * blockDim.x + threadIdx.x; e < E; e += gridDim.x * blockDim.x) {
        int d = coli[e];
        int p = atomicAdd(&cursor[d], 1);
        csr[rowptr[d] + p] = rowi[e];
    }
}

// ---------------- GEMM: xw[i] = rsqrt(deg+1)*(feat[i]@W) -> bf16 -----------
// OUTPUT LAYOUT (feature-sliced, N+1 rows per slice; row N = zero pad):
//   xw[block tt][node i 0..N][m 0..15]  (u16)
__global__ __launch_bounds__(256) void k_gemm(
        const float* __restrict__ feat, const int* __restrict__ deg,
        const u16* __restrict__ Wp, u16* __restrict__ xw, int N) {
    __shared__ u16 atile[64 * 264];      // bf16 tile, row stride 264
    const int t = threadIdx.x, wave = t >> 6, lane = t & 63;
    const int m = lane & 15, q = lane >> 4;
    const int base = blockIdx.x * 64;

    for (int r = wave; r < 64; r += 4) {
        int i = base + r;
        float ax = 0.f, ay = 0.f, az = 0.f, aw = 0.f;
        if (i < N) {
            float di = rsqrtf((float)(deg[i] + 1));
            float4 v = *(const float4*)(feat + (size_t)i * F_IN + lane * 4);
            ax = di * v.x; ay = di * v.y; az = di * v.z; aw = di * v.w;
        }
        // packed f32->bf16x2 conversion (v_cvt_pk_bf16_f32, halves pack VALU)
        __hip_bfloat162 p0 = __float22bfloat162_rn(float2{ax, ay});
        __hip_bfloat162 p1 = __float22bfloat162_rn(float2{az, aw});
        u32* dst = (u32*)(atile + r * 264 + lane * 4);
        dst[0] = *(u32*)&p0;
        dst[1] = *(u32*)&p1;
    }
    __syncthreads();

    floatx4 acc[8];
#pragma unroll
    for (int tt = 0; tt < 8; ++tt) acc[tt] = (floatx4)0.0f;
    const short8* wp = (const short8*)Wp;
#pragma unroll
    for (int kb = 0; kb < 8; ++kb) {
        short8 a0 = *(const short8*)(atile + (wave * 16 + m) * 264 + kb * 32 + q * 8);
#pragma unroll
        for (int tt = 0; tt < 8; ++tt) {
            short8 b = wp[(kb * 8 + tt) * 64 + lane];
            acc[tt] = __builtin_amdgcn_mfma_f32_16x16x32_bf16(a0, b, acc[tt], 0, 0, 0);
        }
    }

#pragma unroll
    for (int r = 0; r < 4; ++r) {
        int orow = base + wave * 16 + q * 4 + r;
        if (orow < N) {
#pragma unroll
            for (int tt = 0; tt < 8; ++tt)
                xw[((size_t)tt * (N + 1) + orow) * 16 + m] = f2bf(acc[tt][r]);
        }
    }
}

// ---------------- aggregation + epilogue + fused h (feature-sliced) --------
// R11 structure (pipelined scalar state, 8 groups x 8 lanes) + float2
// accumulation (coax v_pk_add_f32) + fused k_h via done-counter: the LAST
// block to finish computes the sigmoid epilogue (saves one dispatch).
__global__ __launch_bounds__(256) void k_agg(const u16* __restrict__ xw,
                                             const int* __restrict__ rowptr,
                                             const int* __restrict__ deg,
                                             const int* __restrict__ csr,
                                             const int* __restrict__ csrB,
                                             const float* __restrict__ bvec,
                                             float* __restrict__ out,
                                             float* __restrict__ hsum,
                                             int* __restrict__ done,
                                             float* __restrict__ outh,
                                             float invN, int N) {
    __shared__ float hpart[16];
    __shared__ int lastflag;
    int t = threadIdx.x;
    if (t < 16) hpart[t] = 0.f;
    __syncthreads();
    const int w = blockIdx.x & 7;
    const int stripe = blockIdx.x >> 3;
    const int nstripe = gridDim.x >> 3;
    const int lane = t & 63, wv = t >> 6;
    const int lane7 = lane & 7;            // u32 index within 32B node-slice
    const int g = lane >> 3;               // group (node slot) within wave
    const int gbase = lane & 56;
    const u32* slice = (const u32*)xw + (size_t)w * (N + 1) * 8;
    float b0 = bvec[w * 16 + 2 * lane7], b1 = bvec[w * 16 + 2 * lane7 + 1];
    f32x2 h = (f32x2)0.f;
    const int step = nstripe * 32;

    int i = stripe * 32 + wv * 8 + g;
    // prologue: load state for the first node
    int dd_c = 0, s0_c = 0, sA_c = N, sB_c = N, sC_c = N;
    if (i < N) {
        dd_c = deg[i];
        s0_c = rowptr ? rowptr[i] : i * CA;
        sA_c = csr[s0_c + lane7];
        sB_c = csr[s0_c + 8 + lane7];
        sC_c = csr[s0_c + 16 + lane7];
    }
    while (i < N) {
        // prefetch next node's scalar state (independent of current loads)
        int inext = i + step;
        int dd_n = 0, s0_n = 0, sA_n = N, sB_n = N, sC_n = N;
        if (inext < N) {
            dd_n = deg[inext];
            s0_n = rowptr ? rowptr[inext] : inext * CA;
            sA_n = csr[s0_n + lane7];
            sB_n = csr[s0_n + 8 + lane7];
            sC_n = csr[s0_n + 16 + lane7];
        }
        // process current node
        int dd = dd_c;
        float di = rsqrtf((float)(dd + 1));
        if (!rowptr) dd = dd < CAP ? dd : CAP;
        u32 xs = slice[(u32)(i * 8 + lane7)];
        f32x2 a; a.x = bf_lo(xs); a.y = bf_hi(xs);   // self-loop (pre-scaled)
        int sA = (lane7 < dd)      ? sA_c : N;
        int sB = (lane7 + 8 < dd)  ? sB_c : N;
        int sC = (lane7 + 16 < dd) ? sC_c : N;
        u32 xv[PRE];
#pragma unroll
        for (int u = 0; u < 8; ++u) {
            int sx = __shfl(sA, gbase + u);
            xv[u] = slice[(u32)(sx * 8 + lane7)];
        }
#pragma unroll
        for (int u = 0; u < 8; ++u) {
            int sx = __shfl(sB, gbase + u);
            xv[8 + u] = slice[(u32)(sx * 8 + lane7)];
        }
#pragma unroll
        for (int u = 0; u < 8; ++u) {
            int sx = __shfl(sC, gbase + u);
            xv[16 + u] = slice[(u32)(sx * 8 + lane7)];
        }
#pragma unroll
        for (int u = 0; u < PRE; ++u) {
            f32x2 tv; tv.x = bf_lo(xv[u]); tv.y = bf_hi(xv[u]);
            a += tv;
        }
        // rare tail: any node in the wave with deg > 24
        if (__any(dd > PRE)) {
            int ddmax = dd;
            ddmax = max(ddmax, __shfl_xor(ddmax, 8));
            ddmax = max(ddmax, __shfl_xor(ddmax, 16));
            ddmax = max(ddmax, __shfl_xor(ddmax, 32));
            // shfl from loop-exited lanes is stale -> clamp (capacity bound)
            ddmax = min(ddmax, rowptr ? (1 << 20) : CAP);
            int s0 = s0_c;
            for (int jb = PRE; jb < ddmax; jb += 8) {
                int sxv = N;
                if (jb + lane7 < dd) {
                    if (rowptr) sxv = csr[s0 + jb + lane7];
                    else        sxv = csrB[i * CB + (jb - CA) + lane7];
                }
                u32 yv[8];
#pragma unroll
                for (int u = 0; u < 8; ++u) {
                    int sx = __shfl(sxv, gbase + u);
                    yv[u] = slice[(u32)(sx * 8 + lane7)];
                }
#pragma unroll
                for (int u = 0; u < 8; ++u) {
                    f32x2 tv; tv.x = bf_lo(yv[u]); tv.y = bf_hi(yv[u]);
                    a += tv;
                }
            }
        }
        float o0 = fmaxf(fmaf(a.x, di, b0), 0.f);
        float o1 = fmaxf(fmaf(a.y, di, b1), 0.f);
        h.x += o0; h.y += o1;
        *(float2*)(out + (size_t)i * F_OUT + w * 16 + 2 * lane7) = make_float2(o0, o1);
        // rotate pipeline
        i = inext;
        dd_c = dd_n; s0_c = s0_n; sA_c = sA_n; sB_c = sB_n; sC_c = sC_n;
    }
    atomicAdd(&hpart[2 * lane7], h.x);
    atomicAdd(&hpart[2 * lane7 + 1], h.y);
    __syncthreads();
    if (t < 16) atomicAdd(&hsum[w * 16 + t], hpart[t]);
    __syncthreads();                      // drain this block's hsum atomics
    if (t == 0) {
        __threadfence();                  // release hsum updates
        int old = atomicAdd(done, 1);
        lastflag = (old == (int)gridDim.x - 1);
    }
    __syncthreads();
    if (lastflag) {
        __threadfence();                  // acquire
        if (t < 128) {
            // coherent read across XCD L2s: atomic no-op add returns current
            float mm = atomicAdd(&hsum[t], 0.f) * invN;
            outh[t] = 1.f / (1.f + __expf(-mm));
        }
    }
}

extern "C" void kernel_launch(void* const* d_in, const int* in_sizes, int n_in,
                              void* d_out, int out_size, void* d_ws, size_t ws_size,
                              hipStream_t stream) {
    const float* feat = (const float*)d_in[0];   // fp32 [N,256]
    const int* ei     = (const int*)d_in[1];     // int32 [2,E]
    const float* W    = (const float*)d_in[2];   // fp32 [256,128]
    const float* bvec = (const float*)d_in[3];   // fp32 [128]
    float* out        = (float*)d_out;           // fp32: x_out [N,128] | h [128]

    const int N = in_sizes[0] / F_IN;   // 100000
    const int E = in_sizes[1] / 2;      // 1600000

    char* ws = (char*)d_ws;
    size_t o = 0;
    u16* Wp       = (u16*)(ws + o);   o += (size_t)F_IN * F_OUT * 2;   // 64 KB
    int* deg      = (int*)(ws + o);   o += (size_t)N * 4;
    int* cursor   = (int*)(ws + o);   o += (size_t)N * 4;
    float* hsum   = (float*)(ws + o); o += 512;
    int* done     = (int*)(ws + o);   o += 64;
    int* rowptr   = (int*)(ws + o);   o += (size_t)N * 4;
    int* bsum     = (int*)(ws + o);   o += 1024;
    size_t fixed  = o;

    // choose path by available scratch (call-invariant -> graph-safe)
    size_t xw_bytes = (size_t)(N + 1) * F_OUT * 2;      // N+1 rows (zero pad)
    size_t need_fast = fixed + (size_t)N * (CA + CB) * 4 + xw_bytes;
    bool fast = ws_size >= need_fast + 4096;
    int npw = (N + NWIN - 1) / NWIN;                    // 12500
    float invN = 1.0f / (float)N;
    float* outh = out + (size_t)N * F_OUT;

    if (fast) {
        int* csrA = (int*)(ws + o);   o += (size_t)N * CA * 4;         // 9.6 MB
        int* csrB = (int*)(ws + o);   o += (size_t)N * CB * 4;         // 16.0 MB
        u16* xw   = (u16*)(ws + o);   o += xw_bytes;                   // 25.6 MB

        // k_pack also zeroes cursor+hsum+done (N+128+16 ints, contiguous)
        int nzero = N + 144;
        int packblocks = (32896 + nzero + 255) / 256;
        k_pack<<<packblocks, 256, 0, stream>>>(W, Wp, xw, cursor, nzero, N);
        k_fillcap_xcd<<<4096, 256, 0, stream>>>(ei, ei + E, E, npw, N, cursor,
                                                csrA, csrB);
        int ntiles = (N + 63) / 64;
        k_gemm<<<ntiles, 256, 0, stream>>>(feat, cursor, Wp, xw, N);
        k_agg<<<2048, 256, 0, stream>>>(xw, nullptr, cursor, csrA, csrB,
                                        bvec, out, hsum, done, outh, invN, N);
    } else {
        int* csr = (int*)(ws + o);    o += (size_t)E * 4;              // 6.4 MB
        u16* xw  = (u16*)(ws + o);    o += xw_bytes;                   // 25.6 MB

        // zero deg + cursor + hsum + done (contiguous)
        hipMemsetAsync((char*)deg, 0, (size_t)N * 8 + 576, stream);
        k_pack<<<129, 256, 0, stream>>>(W, Wp, xw, cursor, 0, N);
        k_degree<<<1024, 256, 0, stream>>>(ei + E, E, deg);
        int nb = (N + 1023) / 1024;
        k_blocksum<<<nb, 256, 0, stream>>>(deg, N, bsum);
        k_rowptr<<<nb, 256, 0, stream>>>(deg, N, bsum, nb, rowptr);
        k_fill<<<1024, 256, 0, stream>>>(ei, ei + E, E, rowptr, cursor, csr);
        int ntiles = (N + 63) / 64;
        k_gemm<<<ntiles, 256, 0, stream>>>(feat, deg, Wp, xw, N);
        k_agg<<<2048, 256, 0, stream>>>(xw, rowptr, deg, csr, nullptr,
                                        bvec, out, hsum, done, outh, invN, N);
    }
}

// Round 13
// 344.157 us; speedup vs baseline: 1.1985x; 1.1985x over previous
//
#include <hip/hip_runtime.h>
#include <hip/hip_bf16.h>

typedef __attribute__((ext_vector_type(8))) short short8;
typedef __attribute__((ext_vector_type(4))) float floatx4;
typedef unsigned short u16;
typedef unsigned int u32;

#define F_IN  256
#define F_OUT 128
#define CAP   64          // logical bucket capacity (P(deg>64) ~ 2e-18 for Poisson(16))
#define CA    24          // packed primary slots per node (csrA stride)
#define CB    40          // overflow slots per node (csrB stride), CA+CB=CAP
#define NWIN  8           // destination windows == XCD count (measured, m09)
#define PRE   24          // unconditional gather burst (>= typical wave-max degree)

__device__ __forceinline__ float bf_lo(u32 u) { return __uint_as_float(u << 16); }
__device__ __forceinline__ float bf_hi(u32 u) { return __uint_as_float(u & 0xffff0000u); }
__device__ __forceinline__ u16 f2bf(float f) {
    u32 u = __float_as_uint(f);
    u += 0x7fffu + ((u >> 16) & 1u);   // round-to-nearest-even
    return (u16)(u >> 16);
}

// ---------------- W pack + xw zero-row init + workspace zero ---------------
// gid < 32768: pack W into MFMA B-fragments.
// next 128:    zero the 8 pad rows (row N of each feature-slice) of xw.
// rest:        zero cursor+hsum (replaces hipMemsetAsync dispatch).
__global__ void k_pack(const float* __restrict__ W, u16* __restrict__ Wp,
                       u16* __restrict__ xw, int* __restrict__ zero0,
                       int nzero, int N) {
    int gid = blockIdx.x * 256 + threadIdx.x;
    if (gid < 32768) {
        int f = gid >> 3, j = gid & 7;
        int lane = f & 63, tt = (f >> 6) & 7, kb = f >> 9;
        int m = lane & 15, q = lane >> 4;
        Wp[(size_t)f * 8 + j] = f2bf(W[(kb * 32 + q * 8 + j) * F_OUT + tt * 16 + m]);
    } else if (gid < 32896) {
        int e = gid - 32768;
        int w = e >> 4, m = e & 15;
        xw[((size_t)w * (N + 1) + N) * 16 + m] = 0;   // bf16 zero row
    } else {
        int z = gid - 32896;
        if (z < nzero) zero0[z] = 0;
    }
}

// ---------------- FAST PATH: XCD-windowed packed-csr bucket fill -----------
// Packed csrA [N][24] (dense 96B stride) + overflow csrB [N][40] (~2% nodes).
// 2x unrolled scan, paired loads. Grid 4096: more waves in flight to hide
// L2-atomic latency (kernel is atomic-latency-bound, R0: 0.3% VALU).
__global__ void k_fillcap_xcd(const int* __restrict__ rowi, const int* __restrict__ coli,
                              int E, int npw, int N,
                              int* __restrict__ cursor,
                              int* __restrict__ csrA, int* __restrict__ csrB) {
    int grp  = blockIdx.x & (NWIN - 1);       // ~XCD id under round-robin dispatch
    int gblk = blockIdx.x >> 3;               // block index within group
    int nblk = gridDim.x >> 3;
    int lo = grp * npw;
    int hi = lo + npw; if (hi > N) hi = N;
    const int stride = nblk * blockDim.x;
    int e = gblk * blockDim.x + threadIdx.x;
    for (; e + stride < E; e += 2 * stride) {
        int d0 = coli[e],          r0 = rowi[e];
        int d1 = coli[e + stride], r1 = rowi[e + stride];
        if (d0 >= lo && d0 < hi) {
            int p = atomicAdd(&cursor[d0], 1);
            if (p < CA) csrA[d0 * CA + p] = r0;
            else if (p < CAP) csrB[d0 * CB + (p - CA)] = r0;
        }
        if (d1 >= lo && d1 < hi) {
            int p = atomicAdd(&cursor[d1], 1);
            if (p < CA) csrA[d1 * CA + p] = r1;
            else if (p < CAP) csrB[d1 * CB + (p - CA)] = r1;
        }
    }
    if (e < E) {
        int d = coli[e], r = rowi[e];
        if (d >= lo && d < hi) {
            int p = atomicAdd(&cursor[d], 1);
            if (p < CA) csrA[d * CA + p] = r;
            else if (p < CAP) csrB[d * CB + (p - CA)] = r;
        }
    }
}

// ---------------- FALLBACK PATH: exact CSR (degree + scan + fill) ----------
__global__ void k_degree(const int* __restrict__ col, int E, int* __restrict__ deg) {
    for (int e = blockIdx.x * blockDim.x + threadIdx.x; e < E; e += gridDim.x * blockDim.x)
        atomicAdd(&deg[col[e]], 1);
}

__global__ void k_blocksum(const int* __restrict__ deg, int N, int* __restrict__ bsum) {
    __shared__ int s[256];
    int base = blockIdx.x * 1024, t = threadIdx.x;
    int v = 0;
    for (int i = t; i < 1024; i += 256) { int idx = base + i; v += (idx < N) ? deg[idx] : 0; }
    s[t] = v; __syncthreads();
    for (int off = 128; off > 0; off >>= 1) {
        if (t < off) s[t] += s[t + off];
        __syncthreads();
    }
    if (t == 0) bsum[blockIdx.x] = s[0];
}

__global__ void k_rowptr(const int* __restrict__ deg, int N, const int* __restrict__ bsum,
                         int nb, int* __restrict__ rowptr) {
    __shared__ int s[256];
    __shared__ int sb[256];
    int base = blockIdx.x * 1024, t = threadIdx.x;
    sb[t] = (t < nb && t < blockIdx.x) ? bsum[t] : 0;
    __syncthreads();
    for (int off = 128; off > 0; off >>= 1) {
        if (t < off) sb[t] += sb[t + off];
        __syncthreads();
    }
    int blockbase = sb[0];
    int v[4]; int tot = 0;
#pragma unroll
    for (int j = 0; j < 4; ++j) {
        int idx = base + t * 4 + j;
        v[j] = (idx < N) ? deg[idx] : 0;
        tot += v[j];
    }
    s[t] = tot; __syncthreads();
    for (int off = 1; off < 256; off <<= 1) {
        int x = (t >= off) ? s[t - off] : 0;
        __syncthreads();
        s[t] += x;
        __syncthreads();
    }
    int prefix = blockbase + s[t] - tot;
#pragma unroll
    for (int j = 0; j < 4; ++j) {
        int idx = base + t * 4 + j;
        if (idx < N) rowptr[idx] = prefix;
        prefix += v[j];
    }
}

__global__ void k_fill(const int* __restrict__ rowi, const int* __restrict__ coli, int E,
                       const int* __restrict__ rowptr, int* __restrict__ cursor,
                       int* __restrict__ csr) {
    for (int e = blockIdx.x * blockDim.x + threadIdx.x; e < E; e += gridDim.x * blockDim.x) {
        int d = coli[e];
        int p = atomicAdd(&cursor[d], 1);
        csr[rowptr[d] + p] = rowi[e];
    }
}

// ---------------- GEMM: xw[i] = rsqrt(deg+1)*(feat[i]@W) -> bf16 -----------
// OUTPUT LAYOUT (feature-sliced, N+1 rows per slice; row N = zero pad):
//   xw[block tt][node i 0..N][m 0..15]  (u16)
__global__ __launch_bounds__(256) void k_gemm(
        const float* __restrict__ feat, const int* __restrict__ deg,
        const u16* __restrict__ Wp, u16* __restrict__ xw, int N) {
    __shared__ u16 atile[64 * 264];      // bf16 tile, row stride 264
    const int t = threadIdx.x, wave = t >> 6, lane = t & 63;
    const int m = lane & 15, q = lane >> 4;
    const int base = blockIdx.x * 64;

    for (int r = wave; r < 64; r += 4) {
        int i = base + r;
        float ax = 0.f, ay = 0.f, az = 0.f, aw = 0.f;
        if (i < N) {
            float di = rsqrtf((float)(deg[i] + 1));
            float4 v = *(const float4*)(feat + (size_t)i * F_IN + lane * 4);
            ax = di * v.x; ay = di * v.y; az = di * v.z; aw = di * v.w;
        }
        // packed f32->bf16x2 conversion (v_cvt_pk_bf16_f32, halves pack VALU)
        __hip_bfloat162 p0 = __float22bfloat162_rn(float2{ax, ay});
        __hip_bfloat162 p1 = __float22bfloat162_rn(float2{az, aw});
        u32* dst = (u32*)(atile + r * 264 + lane * 4);
        dst[0] = *(u32*)&p0;
        dst[1] = *(u32*)&p1;
    }
    __syncthreads();

    floatx4 acc[8];
#pragma unroll
    for (int tt = 0; tt < 8; ++tt) acc[tt] = (floatx4)0.0f;
    const short8* wp = (const short8*)Wp;
#pragma unroll
    for (int kb = 0; kb < 8; ++kb) {
        short8 a0 = *(const short8*)(atile + (wave * 16 + m) * 264 + kb * 32 + q * 8);
#pragma unroll
        for (int tt = 0; tt < 8; ++tt) {
            short8 b = wp[(kb * 8 + tt) * 64 + lane];
            acc[tt] = __builtin_amdgcn_mfma_f32_16x16x32_bf16(a0, b, acc[tt], 0, 0, 0);
        }
    }

#pragma unroll
    for (int r = 0; r < 4; ++r) {
        int orow = base + wave * 16 + q * 4 + r;
        if (orow < N) {
#pragma unroll
            for (int tt = 0; tt < 8; ++tt)
                xw[((size_t)tt * (N + 1) + orow) * 16 + m] = f2bf(acc[tt][r]);
        }
    }
}

// ---------------- aggregation + epilogue (feature-sliced, XCD-local) -------
// EXACT R11 form (measured 88.5us @ VGPR 40). R12 post-mortem: f32x2
// accumulator + fused tail shrank allocation to 32 VGPR -> compiler split
// the 24-gather burst into dependent chunks (depth-1 MLP destroyed, 160us).
// Keep scalar a0/a1 chains + separate k_h; register budget is load-bearing.
__global__ __launch_bounds__(256) void k_agg(const u16* __restrict__ xw,
                                             const int* __restrict__ rowptr,
                                             const int* __restrict__ deg,
                                             const int* __restrict__ csr,
                                             const int* __restrict__ csrB,
                                             const float* __restrict__ bvec,
                                             float* __restrict__ out,
                                             float* __restrict__ hsum, int N) {
    __shared__ float hpart[16];
    int t = threadIdx.x;
    if (t < 16) hpart[t] = 0.f;
    __syncthreads();
    const int w = blockIdx.x & 7;
    const int stripe = blockIdx.x >> 3;
    const int nstripe = gridDim.x >> 3;
    const int lane = t & 63, wv = t >> 6;
    const int lane7 = lane & 7;            // u32 index within 32B node-slice
    const int g = lane >> 3;               // group (node slot) within wave
    const int gbase = lane & 56;
    const u32* slice = (const u32*)xw + (size_t)w * (N + 1) * 8;
    float b0 = bvec[w * 16 + 2 * lane7], b1 = bvec[w * 16 + 2 * lane7 + 1];
    float h0 = 0.f, h1 = 0.f;
    const int step = nstripe * 32;

    int i = stripe * 32 + wv * 8 + g;
    // prologue: load state for the first node
    int dd_c = 0, s0_c = 0, sA_c = N, sB_c = N, sC_c = N;
    if (i < N) {
        dd_c = deg[i];
        s0_c = rowptr ? rowptr[i] : i * CA;
        sA_c = csr[s0_c + lane7];
        sB_c = csr[s0_c + 8 + lane7];
        sC_c = csr[s0_c + 16 + lane7];
    }
    while (i < N) {
        // prefetch next node's scalar state (independent of current loads)
        int inext = i + step;
        int dd_n = 0, s0_n = 0, sA_n = N, sB_n = N, sC_n = N;
        if (inext < N) {
            dd_n = deg[inext];
            s0_n = rowptr ? rowptr[inext] : inext * CA;
            sA_n = csr[s0_n + lane7];
            sB_n = csr[s0_n + 8 + lane7];
            sC_n = csr[s0_n + 16 + lane7];
        }
        // process current node
        int dd = dd_c;
        float di = rsqrtf((float)(dd + 1));
        if (!rowptr) dd = dd < CAP ? dd : CAP;
        u32 xs = slice[(u32)(i * 8 + lane7)];
        float a0 = bf_lo(xs), a1 = bf_hi(xs);        // self-loop (pre-scaled)
        int sA = (lane7 < dd)      ? sA_c : N;
        int sB = (lane7 + 8 < dd)  ? sB_c : N;
        int sC = (lane7 + 16 < dd) ? sC_c : N;
        u32 xv[PRE];
#pragma unroll
        for (int u = 0; u < 8; ++u) {
            int sx = __shfl(sA, gbase + u);
            xv[u] = slice[(u32)(sx * 8 + lane7)];
        }
#pragma unroll
        for (int u = 0; u < 8; ++u) {
            int sx = __shfl(sB, gbase + u);
            xv[8 + u] = slice[(u32)(sx * 8 + lane7)];
        }
#pragma unroll
        for (int u = 0; u < 8; ++u) {
            int sx = __shfl(sC, gbase + u);
            xv[16 + u] = slice[(u32)(sx * 8 + lane7)];
        }
#pragma unroll
        for (int u = 0; u < PRE; ++u) { a0 += bf_lo(xv[u]); a1 += bf_hi(xv[u]); }
        // rare tail: any node in the wave with deg > 24
        if (__any(dd > PRE)) {
            int ddmax = dd;
            ddmax = max(ddmax, __shfl_xor(ddmax, 8));
            ddmax = max(ddmax, __shfl_xor(ddmax, 16));
            ddmax = max(ddmax, __shfl_xor(ddmax, 32));
            // shfl from loop-exited lanes is stale -> clamp (capacity bound)
            ddmax = min(ddmax, rowptr ? (1 << 20) : CAP);
            int s0 = s0_c;
            for (int jb = PRE; jb < ddmax; jb += 8) {
                int sxv = N;
                if (jb + lane7 < dd) {
                    if (rowptr) sxv = csr[s0 + jb + lane7];
                    else        sxv = csrB[i * CB + (jb - CA) + lane7];
                }
                u32 yv[8];
#pragma unroll
                for (int u = 0; u < 8; ++u) {
                    int sx = __shfl(sxv, gbase + u);
                    yv[u] = slice[(u32)(sx * 8 + lane7)];
                }
#pragma unroll
                for (int u = 0; u < 8; ++u) { a0 += bf_lo(yv[u]); a1 += bf_hi(yv[u]); }
            }
        }
        float o0 = fmaxf(fmaf(a0, di, b0), 0.f);
        float o1 = fmaxf(fmaf(a1, di, b1), 0.f);
        h0 += o0; h1 += o1;
        *(float2*)(out + (size_t)i * F_OUT + w * 16 + 2 * lane7) = make_float2(o0, o1);
        // rotate pipeline
        i = inext;
        dd_c = dd_n; s0_c = s0_n; sA_c = sA_n; sB_c = sB_n; sC_c = sC_n;
    }
    atomicAdd(&hpart[2 * lane7], h0);
    atomicAdd(&hpart[2 * lane7 + 1], h1);
    __syncthreads();
    if (t < 16) atomicAdd(&hsum[w * 16 + t], hpart[t]);
}

__global__ void k_h(const float* __restrict__ hsum, float* __restrict__ outh, float invN) {
    int t = threadIdx.x;
    if (t < 128) {
        float mm = hsum[t] * invN;
        outh[t] = 1.f / (1.f + __expf(-mm));
    }
}

extern "C" void kernel_launch(void* const* d_in, const int* in_sizes, int n_in,
                              void* d_out, int out_size, void* d_ws, size_t ws_size,
                              hipStream_t stream) {
    const float* feat = (const float*)d_in[0];   // fp32 [N,256]
    const int* ei     = (const int*)d_in[1];     // int32 [2,E]
    const float* W    = (const float*)d_in[2];   // fp32 [256,128]
    const float* bvec = (const float*)d_in[3];   // fp32 [128]
    float* out        = (float*)d_out;           // fp32: x_out [N,128] | h [128]

    const int N = in_sizes[0] / F_IN;   // 100000
    const int E = in_sizes[1] / 2;      // 1600000

    char* ws = (char*)d_ws;
    size_t o = 0;
    u16* Wp       = (u16*)(ws + o);   o += (size_t)F_IN * F_OUT * 2;   // 64 KB
    int* deg      = (int*)(ws + o);   o += (size_t)N * 4;
    int* cursor   = (int*)(ws + o);   o += (size_t)N * 4;
    float* hsum   = (float*)(ws + o); o += 512;
    int* rowptr   = (int*)(ws + o);   o += (size_t)N * 4;
    int* bsum     = (int*)(ws + o);   o += 1024;
    size_t fixed  = o;

    // choose path by available scratch (call-invariant -> graph-safe)
    size_t xw_bytes = (size_t)(N + 1) * F_OUT * 2;      // N+1 rows (zero pad)
    size_t need_fast = fixed + (size_t)N * (CA + CB) * 4 + xw_bytes;
    bool fast = ws_size >= need_fast + 4096;
    int npw = (N + NWIN - 1) / NWIN;                    // 12500
    float invN = 1.0f / (float)N;
    float* outh = out + (size_t)N * F_OUT;

    if (fast) {
        int* csrA = (int*)(ws + o);   o += (size_t)N * CA * 4;         // 9.6 MB
        int* csrB = (int*)(ws + o);   o += (size_t)N * CB * 4;         // 16.0 MB
        u16* xw   = (u16*)(ws + o);   o += xw_bytes;                   // 25.6 MB

        // k_pack also zeroes cursor+hsum (N+128 ints, contiguous)
        int nzero = N + 128;
        int packblocks = (32896 + nzero + 255) / 256;
        k_pack<<<packblocks, 256, 0, stream>>>(W, Wp, xw, cursor, nzero, N);
        k_fillcap_xcd<<<4096, 256, 0, stream>>>(ei, ei + E, E, npw, N, cursor,
                                                csrA, csrB);
        int ntiles = (N + 63) / 64;
        k_gemm<<<ntiles, 256, 0, stream>>>(feat, cursor, Wp, xw, N);
        k_agg<<<2048, 256, 0, stream>>>(xw, nullptr, cursor, csrA, csrB,
                                        bvec, out, hsum, N);
        k_h<<<1, 128, 0, stream>>>(hsum, outh, invN);
    } else {
        int* csr = (int*)(ws + o);    o += (size_t)E * 4;              // 6.4 MB
        u16* xw  = (u16*)(ws + o);    o += xw_bytes;                   // 25.6 MB

        // zero deg + cursor + hsum (contiguous)
        hipMemsetAsync((char*)deg, 0, (size_t)N * 8 + 512, stream);
        k_pack<<<129, 256, 0, stream>>>(W, Wp, xw, cursor, 0, N);
        k_degree<<<1024, 256, 0, stream>>>(ei + E, E, deg);
        int nb = (N + 1023) / 1024;
        k_blocksum<<<nb, 256, 0, stream>>>(deg, N, bsum);
        k_rowptr<<<nb, 256, 0, stream>>>(deg, N, bsum, nb, rowptr);
        k_fill<<<1024, 256, 0, stream>>>(ei, ei + E, E, rowptr, cursor, csr);
        int ntiles = (N + 63) / 64;
        k_gemm<<<ntiles, 256, 0, stream>>>(feat, deg, Wp, xw, N);
        k_agg<<<2048, 256, 0, stream>>>(xw, rowptr, deg, csr, nullptr,
                                        bvec, out, hsum, N);
        k_h<<<1, 128, 0, stream>>>(hsum, outh, invN);
    }
}

// Round 14
// 343.366 us; speedup vs baseline: 1.2013x; 1.0023x over previous
//
#include <hip/hip_runtime.h>
#include <hip/hip_bf16.h>

typedef __attribute__((ext_vector_type(8))) short short8;
typedef __attribute__((ext_vector_type(4))) float floatx4;
typedef unsigned short u16;
typedef unsigned int u32;

#define F_IN  256
#define F_OUT 128
#define CAP   64          // logical bucket capacity (P(deg>64) ~ 2e-18 for Poisson(16))
#define CA    24          // packed primary slots per node (csrA stride)
#define CB    40          // overflow slots per node (csrB stride), CA+CB=CAP
#define NWIN  8           // destination windows == XCD count (measured, m09)
#define PRE   24          // unconditional gather burst (>= typical wave-max degree)

__device__ __forceinline__ float bf_lo(u32 u) { return __uint_as_float(u << 16); }
__device__ __forceinline__ float bf_hi(u32 u) { return __uint_as_float(u & 0xffff0000u); }
__device__ __forceinline__ u16 f2bf(float f) {
    u32 u = __float_as_uint(f);
    u += 0x7fffu + ((u >> 16) & 1u);   // round-to-nearest-even
    return (u16)(u >> 16);
}

// ---------------- W pack + xw zero-row init + workspace zero ---------------
// gid < 32768: pack W into MFMA B-fragments.
// next 128:    zero the 8 pad rows (row N of each feature-slice) of xw.
// rest:        zero cursor+hsum (replaces hipMemsetAsync dispatch).
__global__ void k_pack(const float* __restrict__ W, u16* __restrict__ Wp,
                       u16* __restrict__ xw, int* __restrict__ zero0,
                       int nzero, int N) {
    int gid = blockIdx.x * 256 + threadIdx.x;
    if (gid < 32768) {
        int f = gid >> 3, j = gid & 7;
        int lane = f & 63, tt = (f >> 6) & 7, kb = f >> 9;
        int m = lane & 15, q = lane >> 4;
        Wp[(size_t)f * 8 + j] = f2bf(W[(kb * 32 + q * 8 + j) * F_OUT + tt * 16 + m]);
    } else if (gid < 32896) {
        int e = gid - 32768;
        int w = e >> 4, m = e & 15;
        xw[((size_t)w * (N + 1) + N) * 16 + m] = 0;   // bf16 zero row
    } else {
        int z = gid - 32896;
        if (z < nzero) zero0[z] = 0;
    }
}

// ---------------- FAST PATH: XCD-windowed packed-csr bucket fill -----------
// Packed csrA [N][24] (dense 96B stride) + overflow csrB [N][40] (~2% nodes).
// 2x unrolled scan, grid 4096 (atomic-latency-bound: R0 0.3% VALU).
// R14: rowi loaded CONDITIONALLY — only 1/8 of edges match this group's
// window; unconditional rowi was ~45 MB of useless L3 reads per dispatch.
// The coli->compare->atomic critical path is unchanged.
__global__ void k_fillcap_xcd(const int* __restrict__ rowi, const int* __restrict__ coli,
                              int E, int npw, int N,
                              int* __restrict__ cursor,
                              int* __restrict__ csrA, int* __restrict__ csrB) {
    int grp  = blockIdx.x & (NWIN - 1);       // ~XCD id under round-robin dispatch
    int gblk = blockIdx.x >> 3;               // block index within group
    int nblk = gridDim.x >> 3;
    int lo = grp * npw;
    int hi = lo + npw; if (hi > N) hi = N;
    const int stride = nblk * blockDim.x;
    int e = gblk * blockDim.x + threadIdx.x;
    for (; e + stride < E; e += 2 * stride) {
        int d0 = coli[e];
        int d1 = coli[e + stride];
        bool in0 = (d0 >= lo && d0 < hi);
        bool in1 = (d1 >= lo && d1 < hi);
        if (in0) {
            int r0 = rowi[e];
            int p = atomicAdd(&cursor[d0], 1);
            if (p < CA) csrA[d0 * CA + p] = r0;
            else if (p < CAP) csrB[d0 * CB + (p - CA)] = r0;
        }
        if (in1) {
            int r1 = rowi[e + stride];
            int p = atomicAdd(&cursor[d1], 1);
            if (p < CA) csrA[d1 * CA + p] = r1;
            else if (p < CAP) csrB[d1 * CB + (p - CA)] = r1;
        }
    }
    if (e < E) {
        int d = coli[e];
        if (d >= lo && d < hi) {
            int r = rowi[e];
            int p = atomicAdd(&cursor[d], 1);
            if (p < CA) csrA[d * CA + p] = r;
            else if (p < CAP) csrB[d * CB + (p - CA)] = r;
        }
    }
}

// ---------------- FALLBACK PATH: exact CSR (degree + scan + fill) ----------
__global__ void k_degree(const int* __restrict__ col, int E, int* __restrict__ deg) {
    for (int e = blockIdx.x * blockDim.x + threadIdx.x; e < E; e += gridDim.x * blockDim.x)
        atomicAdd(&deg[col[e]], 1);
}

__global__ void k_blocksum(const int* __restrict__ deg, int N, int* __restrict__ bsum) {
    __shared__ int s[256];
    int base = blockIdx.x * 1024, t = threadIdx.x;
    int v = 0;
    for (int i = t; i < 1024; i += 256) { int idx = base + i; v += (idx < N) ? deg[idx] : 0; }
    s[t] = v; __syncthreads();
    for (int off = 128; off > 0; off >>= 1) {
        if (t < off) s[t] += s[t + off];
        __syncthreads();
    }
    if (t == 0) bsum[blockIdx.x] = s[0];
}

__global__ void k_rowptr(const int* __restrict__ deg, int N, const int* __restrict__ bsum,
                         int nb, int* __restrict__ rowptr) {
    __shared__ int s[256];
    __shared__ int sb[256];
    int base = blockIdx.x * 1024, t = threadIdx.x;
    sb[t] = (t < nb && t < blockIdx.x) ? bsum[t] : 0;
    __syncthreads();
    for (int off = 128; off > 0; off >>= 1) {
        if (t < off) sb[t] += sb[t + off];
        __syncthreads();
    }
    int blockbase = sb[0];
    int v[4]; int tot = 0;
#pragma unroll
    for (int j = 0; j < 4; ++j) {
        int idx = base + t * 4 + j;
        v[j] = (idx < N) ? deg[idx] : 0;
        tot += v[j];
    }
    s[t] = tot; __syncthreads();
    for (int off = 1; off < 256; off <<= 1) {
        int x = (t >= off) ? s[t - off] : 0;
        __syncthreads();
        s[t] += x;
        __syncthreads();
    }
    int prefix = blockbase + s[t] - tot;
#pragma unroll
    for (int j = 0; j < 4; ++j) {
        int idx = base + t * 4 + j;
        if (idx < N) rowptr[idx] = prefix;
        prefix += v[j];
    }
}

__global__ void k_fill(const int* __restrict__ rowi, const int* __restrict__ coli, int E,
                       const int* __restrict__ rowptr, int* __restrict__ cursor,
                       int* __restrict__ csr) {
    for (int e = blockIdx.x * blockDim.x + threadIdx.x; e < E; e += gridDim.x * blockDim.x) {
        int d = coli[e];
        int p = atomicAdd(&cursor[d], 1);
        csr[rowptr[d] + p] = rowi[e];
    }
}

// ---------------- GEMM: xw[i] = rsqrt(deg+1)*(feat[i]@W) -> bf16 -----------
// OUTPUT LAYOUT (feature-sliced, N+1 rows per slice; row N = zero pad):
//   xw[block tt][node i 0..N][m 0..15]  (u16)
__global__ __launch_bounds__(256) void k_gemm(
        const float* __restrict__ feat, const int* __restrict__ deg,
        const u16* __restrict__ Wp, u16* __restrict__ xw, int N) {
    __shared__ u16 atile[64 * 264];      // bf16 tile, row stride 264
    const int t = threadIdx.x, wave = t >> 6, lane = t & 63;
    const int m = lane & 15, q = lane >> 4;
    const int base = blockIdx.x * 64;

    for (int r = wave; r < 64; r += 4) {
        int i = base + r;
        float ax = 0.f, ay = 0.f, az = 0.f, aw = 0.f;
        if (i < N) {
            float di = rsqrtf((float)(deg[i] + 1));
            float4 v = *(const float4*)(feat + (size_t)i * F_IN + lane * 4);
            ax = di * v.x; ay = di * v.y; az = di * v.z; aw = di * v.w;
        }
        // packed f32->bf16x2 conversion (v_cvt_pk_bf16_f32, halves pack VALU)
        __hip_bfloat162 p0 = __float22bfloat162_rn(float2{ax, ay});
        __hip_bfloat162 p1 = __float22bfloat162_rn(float2{az, aw});
        u32* dst = (u32*)(atile + r * 264 + lane * 4);
        dst[0] = *(u32*)&p0;
        dst[1] = *(u32*)&p1;
    }
    __syncthreads();

    floatx4 acc[8];
#pragma unroll
    for (int tt = 0; tt < 8; ++tt) acc[tt] = (floatx4)0.0f;
    const short8* wp = (const short8*)Wp;
#pragma unroll
    for (int kb = 0; kb < 8; ++kb) {
        short8 a0 = *(const short8*)(atile + (wave * 16 + m) * 264 + kb * 32 + q * 8);
#pragma unroll
        for (int tt = 0; tt < 8; ++tt) {
            short8 b = wp[(kb * 8 + tt) * 64 + lane];
            acc[tt] = __builtin_amdgcn_mfma_f32_16x16x32_bf16(a0, b, acc[tt], 0, 0, 0);
        }
    }

#pragma unroll
    for (int r = 0; r < 4; ++r) {
        int orow = base + wave * 16 + q * 4 + r;
        if (orow < N) {
#pragma unroll
            for (int tt = 0; tt < 8; ++tt)
                xw[((size_t)tt * (N + 1) + orow) * 16 + m] = f2bf(acc[tt][r]);
        }
    }
}

// ---------------- aggregation + epilogue (feature-sliced, XCD-local) -------
// EXACT R11 form (measured 88.5us @ VGPR 40) — FROZEN. R12 post-mortem:
// any codegen-touching edit here (f32x2 acc, fused tail) shrank VGPR to 32
// and split the 24-gather burst (160us). Register budget is load-bearing.
__global__ __launch_bounds__(256) void k_agg(const u16* __restrict__ xw,
                                             const int* __restrict__ rowptr,
                                             const int* __restrict__ deg,
                                             const int* __restrict__ csr,
                                             const int* __restrict__ csrB,
                                             const float* __restrict__ bvec,
                                             float* __restrict__ out,
                                             float* __restrict__ hsum, int N) {
    __shared__ float hpart[16];
    int t = threadIdx.x;
    if (t < 16) hpart[t] = 0.f;
    __syncthreads();
    const int w = blockIdx.x & 7;
    const int stripe = blockIdx.x >> 3;
    const int nstripe = gridDim.x >> 3;
    const int lane = t & 63, wv = t >> 6;
    const int lane7 = lane & 7;            // u32 index within 32B node-slice
    const int g = lane >> 3;               // group (node slot) within wave
    const int gbase = lane & 56;
    const u32* slice = (const u32*)xw + (size_t)w * (N + 1) * 8;
    float b0 = bvec[w * 16 + 2 * lane7], b1 = bvec[w * 16 + 2 * lane7 + 1];
    float h0 = 0.f, h1 = 0.f;
    const int step = nstripe * 32;

    int i = stripe * 32 + wv * 8 + g;
    // prologue: load state for the first node
    int dd_c = 0, s0_c = 0, sA_c = N, sB_c = N, sC_c = N;
    if (i < N) {
        dd_c = deg[i];
        s0_c = rowptr ? rowptr[i] : i * CA;
        sA_c = csr[s0_c + lane7];
        sB_c = csr[s0_c + 8 + lane7];
        sC_c = csr[s0_c + 16 + lane7];
    }
    while (i < N) {
        // prefetch next node's scalar state (independent of current loads)
        int inext = i + step;
        int dd_n = 0, s0_n = 0, sA_n = N, sB_n = N, sC_n = N;
        if (inext < N) {
            dd_n = deg[inext];
            s0_n = rowptr ? rowptr[inext] : inext * CA;
            sA_n = csr[s0_n + lane7];
            sB_n = csr[s0_n + 8 + lane7];
            sC_n = csr[s0_n + 16 + lane7];
        }
        // process current node
        int dd = dd_c;
        float di = rsqrtf((float)(dd + 1));
        if (!rowptr) dd = dd < CAP ? dd : CAP;
        u32 xs = slice[(u32)(i * 8 + lane7)];
        float a0 = bf_lo(xs), a1 = bf_hi(xs);        // self-loop (pre-scaled)
        int sA = (lane7 < dd)      ? sA_c : N;
        int sB = (lane7 + 8 < dd)  ? sB_c : N;
        int sC = (lane7 + 16 < dd) ? sC_c : N;
        u32 xv[PRE];
#pragma unroll
        for (int u = 0; u < 8; ++u) {
            int sx = __shfl(sA, gbase + u);
            xv[u] = slice[(u32)(sx * 8 + lane7)];
        }
#pragma unroll
        for (int u = 0; u < 8; ++u) {
            int sx = __shfl(sB, gbase + u);
            xv[8 + u] = slice[(u32)(sx * 8 + lane7)];
        }
#pragma unroll
        for (int u = 0; u < 8; ++u) {
            int sx = __shfl(sC, gbase + u);
            xv[16 + u] = slice[(u32)(sx * 8 + lane7)];
        }
#pragma unroll
        for (int u = 0; u < PRE; ++u) { a0 += bf_lo(xv[u]); a1 += bf_hi(xv[u]); }
        // rare tail: any node in the wave with deg > 24
        if (__any(dd > PRE)) {
            int ddmax = dd;
            ddmax = max(ddmax, __shfl_xor(ddmax, 8));
            ddmax = max(ddmax, __shfl_xor(ddmax, 16));
            ddmax = max(ddmax, __shfl_xor(ddmax, 32));
            // shfl from loop-exited lanes is stale -> clamp (capacity bound)
            ddmax = min(ddmax, rowptr ? (1 << 20) : CAP);
            int s0 = s0_c;
            for (int jb = PRE; jb < ddmax; jb += 8) {
                int sxv = N;
                if (jb + lane7 < dd) {
                    if (rowptr) sxv = csr[s0 + jb + lane7];
                    else        sxv = csrB[i * CB + (jb - CA) + lane7];
                }
                u32 yv[8];
#pragma unroll
                for (int u = 0; u < 8; ++u) {
                    int sx = __shfl(sxv, gbase + u);
                    yv[u] = slice[(u32)(sx * 8 + lane7)];
                }
#pragma unroll
                for (int u = 0; u < 8; ++u) { a0 += bf_lo(yv[u]); a1 += bf_hi(yv[u]); }
            }
        }
        float o0 = fmaxf(fmaf(a0, di, b0), 0.f);
        float o1 = fmaxf(fmaf(a1, di, b1), 0.f);
        h0 += o0; h1 += o1;
        *(float2*)(out + (size_t)i * F_OUT + w * 16 + 2 * lane7) = make_float2(o0, o1);
        // rotate pipeline
        i = inext;
        dd_c = dd_n; s0_c = s0_n; sA_c = sA_n; sB_c = sB_n; sC_c = sC_n;
    }
    atomicAdd(&hpart[2 * lane7], h0);
    atomicAdd(&hpart[2 * lane7 + 1], h1);
    __syncthreads();
    if (t < 16) atomicAdd(&hsum[w * 16 + t], hpart[t]);
}

__global__ void k_h(const float* __restrict__ hsum, float* __restrict__ outh, float invN) {
    int t = threadIdx.x;
    if (t < 128) {
        float mm = hsum[t] * invN;
        outh[t] = 1.f / (1.f + __expf(-mm));
    }
}

extern "C" void kernel_launch(void* const* d_in, const int* in_sizes, int n_in,
                              void* d_out, int out_size, void* d_ws, size_t ws_size,
                              hipStream_t stream) {
    const float* feat = (const float*)d_in[0];   // fp32 [N,256]
    const int* ei     = (const int*)d_in[1];     // int32 [2,E]
    const float* W    = (const float*)d_in[2];   // fp32 [256,128]
    const float* bvec = (const float*)d_in[3];   // fp32 [128]
    float* out        = (float*)d_out;           // fp32: x_out [N,128] | h [128]

    const int N = in_sizes[0] / F_IN;   // 100000
    const int E = in_sizes[1] / 2;      // 1600000

    char* ws = (char*)d_ws;
    size_t o = 0;
    u16* Wp       = (u16*)(ws + o);   o += (size_t)F_IN * F_OUT * 2;   // 64 KB
    int* deg      = (int*)(ws + o);   o += (size_t)N * 4;
    int* cursor   = (int*)(ws + o);   o += (size_t)N * 4;
    float* hsum   = (float*)(ws + o); o += 512;
    int* rowptr   = (int*)(ws + o);   o += (size_t)N * 4;
    int* bsum     = (int*)(ws + o);   o += 1024;
    size_t fixed  = o;

    // choose path by available scratch (call-invariant -> graph-safe)
    size_t xw_bytes = (size_t)(N + 1) * F_OUT * 2;      // N+1 rows (zero pad)
    size_t need_fast = fixed + (size_t)N * (CA + CB) * 4 + xw_bytes;
    bool fast = ws_size >= need_fast + 4096;
    int npw = (N + NWIN - 1) / NWIN;                    // 12500
    float invN = 1.0f / (float)N;
    float* outh = out + (size_t)N * F_OUT;

    if (fast) {
        int* csrA = (int*)(ws + o);   o += (size_t)N * CA * 4;         // 9.6 MB
        int* csrB = (int*)(ws + o);   o += (size_t)N * CB * 4;         // 16.0 MB
        u16* xw   = (u16*)(ws + o);   o += xw_bytes;                   // 25.6 MB

        // k_pack also zeroes cursor+hsum (N+128 ints, contiguous)
        int nzero = N + 128;
        int packblocks = (32896 + nzero + 255) / 256;
        k_pack<<<packblocks, 256, 0, stream>>>(W, Wp, xw, cursor, nzero, N);
        k_fillcap_xcd<<<4096, 256, 0, stream>>>(ei, ei + E, E, npw, N, cursor,
                                                csrA, csrB);
        int ntiles = (N + 63) / 64;
        k_gemm<<<ntiles, 256, 0, stream>>>(feat, cursor, Wp, xw, N);
        k_agg<<<2048, 256, 0, stream>>>(xw, nullptr, cursor, csrA, csrB,
                                        bvec, out, hsum, N);
        k_h<<<1, 128, 0, stream>>>(hsum, outh, invN);
    } else {
        int* csr = (int*)(ws + o);    o += (size_t)E * 4;              // 6.4 MB
        u16* xw  = (u16*)(ws + o);    o += xw_bytes;                   // 25.6 MB

        // zero deg + cursor + hsum (contiguous)
        hipMemsetAsync((char*)deg, 0, (size_t)N * 8 + 512, stream);
        k_pack<<<129, 256, 0, stream>>>(W, Wp, xw, cursor, 0, N);
        k_degree<<<1024, 256, 0, stream>>>(ei + E, E, deg);
        int nb = (N + 1023) / 1024;
        k_blocksum<<<nb, 256, 0, stream>>>(deg, N, bsum);
        k_rowptr<<<nb, 256, 0, stream>>>(deg, N, bsum, nb, rowptr);
        k_fill<<<1024, 256, 0, stream>>>(ei, ei + E, E, rowptr, cursor, csr);
        int ntiles = (N + 63) / 64;
        k_gemm<<<ntiles, 256, 0, stream>>>(feat, deg, Wp, xw, N);
        k_agg<<<2048, 256, 0, stream>>>(xw, rowptr, deg, csr, nullptr,
                                        bvec, out, hsum, N);
        k_h<<<1, 128, 0, stream>>>(hsum, outh, invN);
    }
}

// Round 15
// 328.824 us; speedup vs baseline: 1.2544x; 1.0442x over previous
//
#include <hip/hip_runtime.h>
#include <hip/hip_bf16.h>

typedef __attribute__((ext_vector_type(8))) short short8;
typedef __attribute__((ext_vector_type(4))) float floatx4;
typedef unsigned short u16;
typedef unsigned int u32;
typedef unsigned long long u64;

#define F_IN  256
#define F_OUT 128
#define CAP   64          // logical bucket capacity (P(deg>64) ~ 2e-18 for Poisson(16))
#define CA    24          // packed primary slots per node (csrA stride)
#define CB    40          // overflow slots per node (csrB stride), CA+CB=CAP
#define NWIN  8           // fill windows == XCD count (measured, m09)
#define AWIN  4           // agg feature-windows: 64B node-slices (full-line gathers)
#define PRE   24          // unconditional gather burst (>= typical wave-max degree)

__device__ __forceinline__ float bf_lo(u32 u) { return __uint_as_float(u << 16); }
__device__ __forceinline__ float bf_hi(u32 u) { return __uint_as_float(u & 0xffff0000u); }
__device__ __forceinline__ u16 f2bf(float f) {
    u32 u = __float_as_uint(f);
    u += 0x7fffu + ((u >> 16) & 1u);   // round-to-nearest-even
    return (u16)(u >> 16);
}

// ---------------- W pack + xw zero-row init + workspace zero ---------------
// gid < 32768: pack W into MFMA B-fragments.
// next 128:    zero the 4 pad rows (row N of each 32-u16 feature-slice).
// rest:        zero cursor+hsum (replaces hipMemsetAsync dispatch).
__global__ void k_pack(const float* __restrict__ W, u16* __restrict__ Wp,
                       u16* __restrict__ xw, int* __restrict__ zero0,
                       int nzero, int N) {
    int gid = blockIdx.x * 256 + threadIdx.x;
    if (gid < 32768) {
        int f = gid >> 3, j = gid & 7;
        int lane = f & 63, tt = (f >> 6) & 7, kb = f >> 9;
        int m = lane & 15, q = lane >> 4;
        Wp[(size_t)f * 8 + j] = f2bf(W[(kb * 32 + q * 8 + j) * F_OUT + tt * 16 + m]);
    } else if (gid < 32896) {
        int e = gid - 32768;          // 0..127 = 4 slices x 32 u16
        int w = e >> 5, m = e & 31;
        xw[((size_t)w * (N + 1) + N) * 32 + m] = 0;   // bf16 zero row
    } else {
        int z = gid - 32896;
        if (z < nzero) zero0[z] = 0;
    }
}

// ---------------- FAST PATH: XCD-windowed packed-csr bucket fill -----------
// Packed csrA [N][24] (dense 96B stride) + overflow csrB [N][40] (~2% nodes).
// 2x unrolled scan, grid 4096, conditional rowi (R14: off the atomic path).
__global__ void k_fillcap_xcd(const int* __restrict__ rowi, const int* __restrict__ coli,
                              int E, int npw, int N,
                              int* __restrict__ cursor,
                              int* __restrict__ csrA, int* __restrict__ csrB) {
    int grp  = blockIdx.x & (NWIN - 1);       // ~XCD id under round-robin dispatch
    int gblk = blockIdx.x >> 3;               // block index within group
    int nblk = gridDim.x >> 3;
    int lo = grp * npw;
    int hi = lo + npw; if (hi > N) hi = N;
    const int stride = nblk * blockDim.x;
    int e = gblk * blockDim.x + threadIdx.x;
    for (; e + stride < E; e += 2 * stride) {
        int d0 = coli[e];
        int d1 = coli[e + stride];
        bool in0 = (d0 >= lo && d0 < hi);
        bool in1 = (d1 >= lo && d1 < hi);
        if (in0) {
            int r0 = rowi[e];
            int p = atomicAdd(&cursor[d0], 1);
            if (p < CA) csrA[d0 * CA + p] = r0;
            else if (p < CAP) csrB[d0 * CB + (p - CA)] = r0;
        }
        if (in1) {
            int r1 = rowi[e + stride];
            int p = atomicAdd(&cursor[d1], 1);
            if (p < CA) csrA[d1 * CA + p] = r1;
            else if (p < CAP) csrB[d1 * CB + (p - CA)] = r1;
        }
    }
    if (e < E) {
        int d = coli[e];
        if (d >= lo && d < hi) {
            int r = rowi[e];
            int p = atomicAdd(&cursor[d], 1);
            if (p < CA) csrA[d * CA + p] = r;
            else if (p < CAP) csrB[d * CB + (p - CA)] = r;
        }
    }
}

// ---------------- FALLBACK PATH: exact CSR (degree + scan + fill) ----------
__global__ void k_degree(const int* __restrict__ col, int E, int* __restrict__ deg) {
    for (int e = blockIdx.x * blockDim.x + threadIdx.x; e < E; e += gridDim.x * blockDim.x)
        atomicAdd(&deg[col[e]], 1);
}

__global__ void k_blocksum(const int* __restrict__ deg, int N, int* __restrict__ bsum) {
    __shared__ int s[256];
    int base = blockIdx.x * 1024, t = threadIdx.x;
    int v = 0;
    for (int i = t; i < 1024; i += 256) { int idx = base + i; v += (idx < N) ? deg[idx] : 0; }
    s[t] = v; __syncthreads();
    for (int off = 128; off > 0; off >>= 1) {
        if (t < off) s[t] += s[t + off];
        __syncthreads();
    }
    if (t == 0) bsum[blockIdx.x] = s[0];
}

__global__ void k_rowptr(const int* __restrict__ deg, int N, const int* __restrict__ bsum,
                         int nb, int* __restrict__ rowptr) {
    __shared__ int s[256];
    __shared__ int sb[256];
    int base = blockIdx.x * 1024, t = threadIdx.x;
    sb[t] = (t < nb && t < blockIdx.x) ? bsum[t] : 0;
    __syncthreads();
    for (int off = 128; off > 0; off >>= 1) {
        if (t < off) sb[t] += sb[t + off];
        __syncthreads();
    }
    int blockbase = sb[0];
    int v[4]; int tot = 0;
#pragma unroll
    for (int j = 0; j < 4; ++j) {
        int idx = base + t * 4 + j;
        v[j] = (idx < N) ? deg[idx] : 0;
        tot += v[j];
    }
    s[t] = tot; __syncthreads();
    for (int off = 1; off < 256; off <<= 1) {
        int x = (t >= off) ? s[t - off] : 0;
        __syncthreads();
        s[t] += x;
        __syncthreads();
    }
    int prefix = blockbase + s[t] - tot;
#pragma unroll
    for (int j = 0; j < 4; ++j) {
        int idx = base + t * 4 + j;
        if (idx < N) rowptr[idx] = prefix;
        prefix += v[j];
    }
}

__global__ void k_fill(const int* __restrict__ rowi, const int* __restrict__ coli, int E,
                       const int* __restrict__ rowptr, int* __restrict__ cursor,
                       int* __restrict__ csr) {
    for (int e = blockIdx.x * blockDim.x + threadIdx.x; e < E; e += gridDim.x * blockDim.x) {
        int d = coli[e];
        int p = atomicAdd(&cursor[d], 1);
        csr[rowptr[d] + p] = rowi[e];
    }
}

// ---------------- GEMM: xw[i] = rsqrt(deg+1)*(feat[i]@W) -> bf16 -----------
// OUTPUT LAYOUT (4 feature-slices of 64B, N+1 rows; row N = zero pad):
//   xw[slice s][node i 0..N][p 0..31] (u16), feature = s*32 + p
__global__ __launch_bounds__(256) void k_gemm(
        const float* __restrict__ feat, const int* __restrict__ deg,
        const u16* __restrict__ Wp, u16* __restrict__ xw, int N) {
    __shared__ u16 atile[64 * 264];      // bf16 tile, row stride 264
    const int t = threadIdx.x, wave = t >> 6, lane = t & 63;
    const int m = lane & 15, q = lane >> 4;
    const int base = blockIdx.x * 64;

    for (int r = wave; r < 64; r += 4) {
        int i = base + r;
        float ax = 0.f, ay = 0.f, az = 0.f, aw = 0.f;
        if (i < N) {
            float di = rsqrtf((float)(deg[i] + 1));
            float4 v = *(const float4*)(feat + (size_t)i * F_IN + lane * 4);
            ax = di * v.x; ay = di * v.y; az = di * v.z; aw = di * v.w;
        }
        // packed f32->bf16x2 conversion (v_cvt_pk_bf16_f32, halves pack VALU)
        __hip_bfloat162 p0 = __float22bfloat162_rn(float2{ax, ay});
        __hip_bfloat162 p1 = __float22bfloat162_rn(float2{az, aw});
        u32* dst = (u32*)(atile + r * 264 + lane * 4);
        dst[0] = *(u32*)&p0;
        dst[1] = *(u32*)&p1;
    }
    __syncthreads();

    floatx4 acc[8];
#pragma unroll
    for (int tt = 0; tt < 8; ++tt) acc[tt] = (floatx4)0.0f;
    const short8* wp = (const short8*)Wp;
#pragma unroll
    for (int kb = 0; kb < 8; ++kb) {
        short8 a0 = *(const short8*)(atile + (wave * 16 + m) * 264 + kb * 32 + q * 8);
#pragma unroll
        for (int tt = 0; tt < 8; ++tt) {
            short8 b = wp[(kb * 8 + tt) * 64 + lane];
            acc[tt] = __builtin_amdgcn_mfma_f32_16x16x32_bf16(a0, b, acc[tt], 0, 0, 0);
        }
    }

#pragma unroll
    for (int r = 0; r < 4; ++r) {
        int orow = base + wave * 16 + q * 4 + r;
        if (orow < N) {
#pragma unroll
            for (int tt = 0; tt < 8; ++tt)
                xw[((size_t)(tt >> 1) * (N + 1) + orow) * 32 + (tt & 1) * 16 + m]
                    = f2bf(acc[tt][r]);
        }
    }
}

// ---------------- aggregation + epilogue (4x64B slices, full-line gathers) -
// R15: SAME R11 skeleton (8 groups x 8 lanes, sA/sB/sC, 24-burst, pipelined
// scalar state — R12 lesson: this structure's regalloc is load-bearing) but
// each lane owns a u64 (8B) of a 64B node-slice: every gather line is fully
// used and only AWIN=4 windows exist -> line-touches E*8 -> E*4 (halved),
// wave-iters/shuffles/VMEM instrs halved, VALU adds invariant.
__global__ __launch_bounds__(256) void k_agg(const u16* __restrict__ xw,
                                             const int* __restrict__ rowptr,
                                             const int* __restrict__ deg,
                                             const int* __restrict__ csr,
                                             const int* __restrict__ csrB,
                                             const float* __restrict__ bvec,
                                             float* __restrict__ out,
                                             float* __restrict__ hsum, int N) {
    __shared__ float hpart[32];
    int t = threadIdx.x;
    if (t < 32) hpart[t] = 0.f;
    __syncthreads();
    const int w = blockIdx.x & (AWIN - 1);
    const int stripe = blockIdx.x >> 2;
    const int nstripe = gridDim.x >> 2;
    const int lane = t & 63, wv = t >> 6;
    const int lane7 = lane & 7;            // u64 slot within 64B node-slice
    const int g = lane >> 3;               // group (node slot) within wave
    const int gbase = lane & 56;
    const u32* slice = (const u32*)xw + (size_t)w * (N + 1) * 16;
    const float4 bv = *(const float4*)(bvec + w * 32 + lane7 * 4);
    float h0 = 0.f, h1 = 0.f, h2 = 0.f, h3 = 0.f;
    const int step = nstripe * 32;

    int i = stripe * 32 + wv * 8 + g;
    // prologue: load state for the first node
    int dd_c = 0, s0_c = 0, sA_c = N, sB_c = N, sC_c = N;
    if (i < N) {
        dd_c = deg[i];
        s0_c = rowptr ? rowptr[i] : i * CA;
        sA_c = csr[s0_c + lane7];
        sB_c = csr[s0_c + 8 + lane7];
        sC_c = csr[s0_c + 16 + lane7];
    }
    while (i < N) {
        // prefetch next node's scalar state (independent of current loads)
        int inext = i + step;
        int dd_n = 0, s0_n = 0, sA_n = N, sB_n = N, sC_n = N;
        if (inext < N) {
            dd_n = deg[inext];
            s0_n = rowptr ? rowptr[inext] : inext * CA;
            sA_n = csr[s0_n + lane7];
            sB_n = csr[s0_n + 8 + lane7];
            sC_n = csr[s0_n + 16 + lane7];
        }
        // process current node
        int dd = dd_c;
        float di = rsqrtf((float)(dd + 1));
        if (!rowptr) dd = dd < CAP ? dd : CAP;
        u64 xs = *(const u64*)(slice + (u32)(i * 16) + lane7 * 2);   // self
        u32 xsl = (u32)xs, xsh = (u32)(xs >> 32);
        float a0 = bf_lo(xsl), a1 = bf_hi(xsl), a2 = bf_lo(xsh), a3 = bf_hi(xsh);
        int sA = (lane7 < dd)      ? sA_c : N;
        int sB = (lane7 + 8 < dd)  ? sB_c : N;
        int sC = (lane7 + 16 < dd) ? sC_c : N;
        u64 xv[PRE];
#pragma unroll
        for (int u = 0; u < 8; ++u) {
            int sx = __shfl(sA, gbase + u);
            xv[u] = *(const u64*)(slice + (u32)(sx * 16) + lane7 * 2);
        }
#pragma unroll
        for (int u = 0; u < 8; ++u) {
            int sx = __shfl(sB, gbase + u);
            xv[8 + u] = *(const u64*)(slice + (u32)(sx * 16) + lane7 * 2);
        }
#pragma unroll
        for (int u = 0; u < 8; ++u) {
            int sx = __shfl(sC, gbase + u);
            xv[16 + u] = *(const u64*)(slice + (u32)(sx * 16) + lane7 * 2);
        }
#pragma unroll
        for (int u = 0; u < PRE; ++u) {
            u32 lo = (u32)xv[u], hi = (u32)(xv[u] >> 32);
            a0 += bf_lo(lo); a1 += bf_hi(lo); a2 += bf_lo(hi); a3 += bf_hi(hi);
        }
        // rare tail: any node in the wave with deg > 24
        if (__any(dd > PRE)) {
            int ddmax = dd;
            ddmax = max(ddmax, __shfl_xor(ddmax, 8));
            ddmax = max(ddmax, __shfl_xor(ddmax, 16));
            ddmax = max(ddmax, __shfl_xor(ddmax, 32));
            // shfl from loop-exited lanes is stale -> clamp (capacity bound)
            ddmax = min(ddmax, rowptr ? (1 << 20) : CAP);
            int s0 = s0_c;
            for (int jb = PRE; jb < ddmax; jb += 8) {
                int sxv = N;
                if (jb + lane7 < dd) {
                    if (rowptr) sxv = csr[s0 + jb + lane7];
                    else        sxv = csrB[i * CB + (jb - CA) + lane7];
                }
                u64 yv[8];
#pragma unroll
                for (int u = 0; u < 8; ++u) {
                    int sx = __shfl(sxv, gbase + u);
                    yv[u] = *(const u64*)(slice + (u32)(sx * 16) + lane7 * 2);
                }
#pragma unroll
                for (int u = 0; u < 8; ++u) {
                    u32 lo = (u32)yv[u], hi = (u32)(yv[u] >> 32);
                    a0 += bf_lo(lo); a1 += bf_hi(lo); a2 += bf_lo(hi); a3 += bf_hi(hi);
                }
            }
        }
        float o0 = fmaxf(fmaf(a0, di, bv.x), 0.f);
        float o1 = fmaxf(fmaf(a1, di, bv.y), 0.f);
        float o2 = fmaxf(fmaf(a2, di, bv.z), 0.f);
        float o3 = fmaxf(fmaf(a3, di, bv.w), 0.f);
        h0 += o0; h1 += o1; h2 += o2; h3 += o3;
        *(float4*)(out + (size_t)i * F_OUT + w * 32 + lane7 * 4) =
            make_float4(o0, o1, o2, o3);
        // rotate pipeline
        i = inext;
        dd_c = dd_n; s0_c = s0_n; sA_c = sA_n; sB_c = sB_n; sC_c = sC_n;
    }
    atomicAdd(&hpart[lane7 * 4 + 0], h0);
    atomicAdd(&hpart[lane7 * 4 + 1], h1);
    atomicAdd(&hpart[lane7 * 4 + 2], h2);
    atomicAdd(&hpart[lane7 * 4 + 3], h3);
    __syncthreads();
    if (t < 32) atomicAdd(&hsum[w * 32 + t], hpart[t]);
}

__global__ void k_h(const float* __restrict__ hsum, float* __restrict__ outh, float invN) {
    int t = threadIdx.x;
    if (t < 128) {
        float mm = hsum[t] * invN;
        outh[t] = 1.f / (1.f + __expf(-mm));
    }
}

extern "C" void kernel_launch(void* const* d_in, const int* in_sizes, int n_in,
                              void* d_out, int out_size, void* d_ws, size_t ws_size,
                              hipStream_t stream) {
    const float* feat = (const float*)d_in[0];   // fp32 [N,256]
    const int* ei     = (const int*)d_in[1];     // int32 [2,E]
    const float* W    = (const float*)d_in[2];   // fp32 [256,128]
    const float* bvec = (const float*)d_in[3];   // fp32 [128]
    float* out        = (float*)d_out;           // fp32: x_out [N,128] | h [128]

    const int N = in_sizes[0] / F_IN;   // 100000
    const int E = in_sizes[1] / 2;      // 1600000

    char* ws = (char*)d_ws;
    size_t o = 0;
    u16* Wp       = (u16*)(ws + o);   o += (size_t)F_IN * F_OUT * 2;   // 64 KB
    int* deg      = (int*)(ws + o);   o += (size_t)N * 4;
    int* cursor   = (int*)(ws + o);   o += (size_t)N * 4;
    float* hsum   = (float*)(ws + o); o += 512;
    int* rowptr   = (int*)(ws + o);   o += (size_t)N * 4;
    int* bsum     = (int*)(ws + o);   o += 1024;
    size_t fixed  = o;

    // choose path by available scratch (call-invariant -> graph-safe)
    size_t xw_bytes = (size_t)(N + 1) * F_OUT * 2;      // N+1 rows (zero pad)
    size_t need_fast = fixed + (size_t)N * (CA + CB) * 4 + xw_bytes;
    bool fast = ws_size >= need_fast + 4096;
    int npw = (N + NWIN - 1) / NWIN;                    // 12500
    float invN = 1.0f / (float)N;
    float* outh = out + (size_t)N * F_OUT;

    if (fast) {
        int* csrA = (int*)(ws + o);   o += (size_t)N * CA * 4;         // 9.6 MB
        int* csrB = (int*)(ws + o);   o += (size_t)N * CB * 4;         // 16.0 MB
        u16* xw   = (u16*)(ws + o);   o += xw_bytes;                   // 25.6 MB

        // k_pack also zeroes cursor+hsum (N+128 ints, contiguous)
        int nzero = N + 128;
        int packblocks = (32896 + nzero + 255) / 256;
        k_pack<<<packblocks, 256, 0, stream>>>(W, Wp, xw, cursor, nzero, N);
        k_fillcap_xcd<<<4096, 256, 0, stream>>>(ei, ei + E, E, npw, N, cursor,
                                                csrA, csrB);
        int ntiles = (N + 63) / 64;
        k_gemm<<<ntiles, 256, 0, stream>>>(feat, cursor, Wp, xw, N);
        k_agg<<<2048, 256, 0, stream>>>(xw, nullptr, cursor, csrA, csrB,
                                        bvec, out, hsum, N);
        k_h<<<1, 128, 0, stream>>>(hsum, outh, invN);
    } else {
        int* csr = (int*)(ws + o);    o += (size_t)E * 4;              // 6.4 MB
        u16* xw  = (u16*)(ws + o);    o += xw_bytes;                   // 25.6 MB

        // zero deg + cursor + hsum (contiguous)
        hipMemsetAsync((char*)deg, 0, (size_t)N * 8 + 512, stream);
        k_pack<<<129, 256, 0, stream>>>(W, Wp, xw, cursor, 0, N);
        k_degree<<<1024, 256, 0, stream>>>(ei + E, E, deg);
        int nb = (N + 1023) / 1024;
        k_blocksum<<<nb, 256, 0, stream>>>(deg, N, bsum);
        k_rowptr<<<nb, 256, 0, stream>>>(deg, N, bsum, nb, rowptr);
        k_fill<<<1024, 256, 0, stream>>>(ei, ei + E, E, rowptr, cursor, csr);
        int ntiles = (N + 63) / 64;
        k_gemm<<<ntiles, 256, 0, stream>>>(feat, deg, Wp, xw, N);
        k_agg<<<2048, 256, 0, stream>>>(xw, rowptr, deg, csr, nullptr,
                                        bvec, out, hsum, N);
        k_h<<<1, 128, 0, stream>>>(hsum, outh, invN);
    }
}